// Round 13
// baseline (67.914 us; speedup 1.0000x reference)
//
#include <hip/hip_runtime.h>

// VecLocal2d R13: structural pivot. W fragment-packing moved to a streaming
// pre-pass (t3); main kernel is barrier-free (one epilogue barrier), LDS-free
// on the operand path, with direct fused-bias fp32 output (t2 + co deleted).
//
// fast3 path (ws >= 49.6 MB):
//   hz:  zero halo planes of xc
//   t1l: x[bk][c][h][w] fp32 -> xc[(h+1)][(w+1)][bk][c] bf16 (LINEAR)
//   t3:  w[pix][o][f] fp32 -> wpack[pix][kc][nt][lane][8] bf16 (MFMA frag
//        layout, f' = cell*32+c) — coalesced read + coalesced write
//   mf:  per-pixel GEMM. wave=(pix,mh). W-frags: dense 1KB loads from wpack
//        (HBM-read once). A-frags: dense 16B loads from xc (L2-resident, no
//        duplication). 180 MFMA/wave. Epilogue: LDS transpose [p][o][bk162]
//        -> float4-over-pix out stores + fused bias. XCD swizzle: all 8
//        jt-blocks of an i on one XCD so 16B/line stores merge in L2.
// midpath (ws >= 32.3 MB): R7 pipeline (proven 52.4us).
// fallback (ws >= 10 MB): R3 (proven).

#define HW    32
#define CIN   32
#define COUT  64
#define FDIM  288
#define FPAD  296
#define NBK   160
#define HP    34
#define PLANE (NBK * CIN)      // 5120 shorts per (ih,jw) plane
#define SLOT_SH (3 * PLANE)
#define WOFF  (4 * SLOT_SH)
#define WPK   18432            // shorts per pixel in wpack (9*4*64*8)
#define BKP   162              // padded bk dim in epilogue LDS

using f32x4  = __attribute__((ext_vector_type(4))) float;
using bf16x8 = __attribute__((ext_vector_type(8))) short;
using s16x4  = __attribute__((ext_vector_type(4))) short;

static __device__ inline unsigned short f2bf(float f) {
    unsigned u = __float_as_uint(f);
    u += 0x7FFFu + ((u >> 16) & 1u);   // round-to-nearest-even
    return (unsigned short)(u >> 16);
}
static __device__ inline float bf2f(short h) {
    return __uint_as_float(((unsigned)(unsigned short)h) << 16);
}
static __device__ inline void gl_lds16(const short* src, short* dst) {
    __builtin_amdgcn_global_load_lds(
        (const __attribute__((address_space(1))) unsigned int*)src,
        (__attribute__((address_space(3))) unsigned int*)dst, 16, 0, 0);
}
static constexpr size_t XC_BYTES = (size_t)HP * HP * PLANE * 2;       // 11,837,440
static constexpr size_t WP_BYTES = (size_t)1024 * WPK * 2;            // 37,748,736
static constexpr size_t CO_BYTES = (size_t)1024 * COUT * NBK * 2;     // 20,971,520

// ---- hz: zero halo planes ----
__global__ __launch_bounds__(256) void hz_kernel(short* __restrict__ xc)
{
    const int id = blockIdx.x;
    int h, w;
    if (id < 34)      { h = 0;  w = id; }
    else if (id < 68) { h = 33; w = id - 34; }
    else { const int e = id - 68; h = 1 + (e >> 1); w = (e & 1) * 33; }
    uint2* p = reinterpret_cast<uint2*>(xc + (size_t)(h * HP + w) * PLANE);
    const uint2 z = {0u, 0u};
#pragma unroll
    for (int r = 0; r < 5; ++r)
        p[threadIdx.x + r * 256] = z;
}

// ---- t1l: x -> xc halo layout, LINEAR planes ----
__global__ __launch_bounds__(256) void t1l_kernel(
    const float* __restrict__ x, short* __restrict__ xc)
{
    __shared__ short tile[HW][36];
    const int bid = blockIdx.x;      // 5120 = bk(160) * h(32)
    const int bk  = bid >> 5;
    const int h   = bid & 31;
    const int tid = threadIdx.x;
    {
        const int c  = tid >> 3;
        const int w4 = (tid & 7) * 4;
        const float4 v = *reinterpret_cast<const float4*>(
            x + (size_t)(bk * 32 + c) * 1024 + h * 32 + w4);
        tile[w4 + 0][c] = (short)f2bf(v.x);
        tile[w4 + 1][c] = (short)f2bf(v.y);
        tile[w4 + 2][c] = (short)f2bf(v.z);
        tile[w4 + 3][c] = (short)f2bf(v.w);
    }
    __syncthreads();
    {
        const int w  = tid >> 3;
        const int cq = tid & 7;
        const uint2 pk = *reinterpret_cast<const uint2*>(&tile[w][cq * 4]);
        *reinterpret_cast<uint2*>(
            xc + (size_t)((h + 1) * HP + (w + 1)) * PLANE + bk * CIN + cq * 4) = pk;
    }
}

// ---- t3: w -> wpack (MFMA fragment layout) ----
__global__ __launch_bounds__(256) void t3_kernel(
    const float* __restrict__ w, short* __restrict__ wpack)
{
    __shared__ short Wl[COUT * FPAD];   // [o][cell*32 + c]
    const int pix = blockIdx.x;
    const int tid = threadIdx.x;

    {   // stage 1: coalesced read + f' reorder into LDS
        const float* wp = w + (size_t)pix * (COUT * FDIM);
#pragma unroll
        for (int q = 0; q < 18; ++q) {        // 4608 float4 / 256 thr
            const int g  = tid + q * 256;
            const int o  = g / 72;
            const int f4 = (g - o * 72) * 4;
            const float4 v = *reinterpret_cast<const float4*>(wp + o * FDIM + f4);
            const float vv[4] = {v.x, v.y, v.z, v.w};
            short* wrow = &Wl[o * FPAD];
#pragma unroll
            for (int e = 0; e < 4; ++e) {
                const int f = f4 + e;
                const int c = f / 9;
                const int cell = f - c * 9;
                wrow[cell * 32 + c] = (short)f2bf(vv[e]);
            }
        }
    }
    __syncthreads();
    {   // stage 2: emit fragments, coalesced 16B writes
        short* dst = wpack + (size_t)pix * WPK;
#pragma unroll
        for (int q = 0; q < 9; ++q) {         // 2304 chunks / 256 thr
            const int u    = tid + q * 256;
            const int kc   = u >> 8;          // /256
            const int rem  = u & 255;
            const int nt   = rem >> 6;
            const int lane = rem & 63;
            const int l15  = lane & 15;
            const int lg   = lane >> 4;
            const s16x4* src = reinterpret_cast<const s16x4*>(
                &Wl[(nt * 16 + l15) * FPAD + kc * 32 + lg * 8]);
            *reinterpret_cast<s16x4*>(dst + (size_t)u * 8 + 0) = src[0];
            *reinterpret_cast<s16x4*>(dst + (size_t)u * 8 + 4) = src[1];
        }
    }
}

// ---- mf: barrier-free main, direct fused output ----
__global__ __launch_bounds__(512) void local2d_f_kernel(
    const short* __restrict__ xc,
    const short* __restrict__ wpack,
    const float* __restrict__ bias,
    float* __restrict__ out)
{
    __shared__ short col[4 * COUT * BKP];     // 82,944 B epilogue transpose

    const int hb = blockIdx.x;                // 256
    // same-i blocks -> same XCD class (hb mod 8): i = (hb&7)*4 + hb>>6
    const int i  = (hb & 7) * 4 + (hb >> 6);
    const int jt = (hb >> 3) & 7;
    const int j0 = jt * 4;
    const int tid = threadIdx.x;

    const int wave = tid >> 6;
    const int lane = tid & 63;
    const int p    = wave >> 1;               // pixel in j-tile
    const int mh   = wave & 1;                // bk half
    const int l15  = lane & 15;
    const int lg   = lane >> 4;
    const int lg8  = lg * 8;
    const int j    = j0 + p;
    const int pix  = i * 32 + j;

    const short* xbase = xc + ((size_t)i * HP + j) * PLANE
                            + (mh * 80 + l15) * CIN + lg8;
    const short* wpb = wpack + (size_t)pix * WPK + lane * 8;

    f32x4 acc[5][4];
#pragma unroll
    for (int mt = 0; mt < 5; ++mt)
#pragma unroll
        for (int nt = 0; nt < 4; ++nt)
#pragma unroll
            for (int r = 0; r < 4; ++r) acc[mt][nt][r] = 0.f;

#pragma unroll
    for (int kc = 0; kc < 9; ++kc) {
        const int kh = kc / 3;
        const int kw = kc - kh * 3;
        const short* ap = xbase + (kh * HP + kw) * PLANE;
        bf16x8 a[5];
#pragma unroll
        for (int mt = 0; mt < 5; ++mt)
            a[mt] = *reinterpret_cast<const bf16x8*>(ap + mt * 512);
        bf16x8 b[4];
#pragma unroll
        for (int nt = 0; nt < 4; ++nt)
            b[nt] = *reinterpret_cast<const bf16x8*>(wpb + (kc * 4 + nt) * 512);
#pragma unroll
        for (int nt = 0; nt < 4; ++nt)
#pragma unroll
            for (int mt = 0; mt < 5; ++mt)
                acc[mt][nt] = __builtin_amdgcn_mfma_f32_16x16x32_bf16(
                    a[mt], b[nt], acc[mt][nt], 0, 0, 0);
    }

    // ---- epilogue: LDS transpose -> float4-over-pix stores, bias fused ----
#pragma unroll
    for (int nt = 0; nt < 4; ++nt) {
        const int o = nt * 16 + l15;
#pragma unroll
        for (int mt = 0; mt < 5; ++mt) {
            s16x4 s;
            s.x = (short)f2bf(acc[mt][nt][0]); s.y = (short)f2bf(acc[mt][nt][1]);
            s.z = (short)f2bf(acc[mt][nt][2]); s.w = (short)f2bf(acc[mt][nt][3]);
            *reinterpret_cast<s16x4*>(
                &col[(p * COUT + o) * BKP + mh * 80 + mt * 16 + lg * 4]) = s;
        }
    }
    __syncthreads();

    const int pix0 = i * 32 + j0;
#pragma unroll
    for (int s = 0; s < 20; ++s) {
        const int id = tid + s * 512;         // 10240 (bk,o) pairs
        const int o  = id & 63;
        const int bk = id >> 6;
        const int k  = bk % 10;
        const float4 bv = *reinterpret_cast<const float4*>(
            bias + (((size_t)(k * COUT + o)) << 10) + pix0);
        float4 r;
        r.x = bf2f(col[(0 * COUT + o) * BKP + bk]) + bv.x;
        r.y = bf2f(col[(1 * COUT + o) * BKP + bk]) + bv.y;
        r.z = bf2f(col[(2 * COUT + o) * BKP + bk]) + bv.z;
        r.w = bf2f(col[(3 * COUT + o) * BKP + bk]) + bv.w;
        *reinterpret_cast<float4*>(
            out + (((size_t)(bk * COUT + o)) << 10) + pix0) = r;
    }
}

// ================= midpath (R7, proven 52.4us; needs 32.3 MB) =================
__global__ __launch_bounds__(256) void t1s_kernel(
    const float* __restrict__ x, short* __restrict__ xc)
{
    __shared__ short tile[HW][36];
    const int bid = blockIdx.x;
    const int bk  = bid >> 5;
    const int h   = bid & 31;
    const int tid = threadIdx.x;
    {
        const int c  = tid >> 3;
        const int w4 = (tid & 7) * 4;
        const float4 v = *reinterpret_cast<const float4*>(
            x + (size_t)(bk * 32 + c) * 1024 + h * 32 + w4);
        tile[w4 + 0][c] = (short)f2bf(v.x);
        tile[w4 + 1][c] = (short)f2bf(v.y);
        tile[w4 + 2][c] = (short)f2bf(v.z);
        tile[w4 + 3][c] = (short)f2bf(v.w);
    }
    __syncthreads();
    {
        const int w  = tid >> 3;
        const int cq = tid & 7;
        const uint2 pk = *reinterpret_cast<const uint2*>(&tile[w][cq * 4]);
        const int sidx = bk * 32 + ((cq * 4) ^ (((bk >> 1) & 3) << 3));
        *reinterpret_cast<uint2*>(
            xc + (size_t)((h + 1) * HP + (w + 1)) * PLANE + sidx) = pk;
    }
}

__global__ __launch_bounds__(512) void local2d_m_kernel(
    const short* __restrict__ xc,
    const float* __restrict__ w,
    short* __restrict__ co)
{
    __shared__ __align__(1024) short Sl[WOFF + COUT * FPAD];
    const int hb = blockIdx.x;
    const int lb = (hb & 7) * 32 + (hb >> 3);
    const int i  = lb >> 3;
    const int jt = lb & 7;
    const int j0 = jt * 4;
    const int tid = threadIdx.x;
    const int wave = tid >> 6;
    const int lane = tid & 63;
    const int nt   = wave & 3;
    const int mh   = wave >> 2;
    const int l15  = lane & 15;
    const int lg   = lane >> 4;
    const int lg8  = lg * 8;
    short* WL = Sl + WOFF;
    int rowbyte[5];
#pragma unroll
    for (int mt = 0; mt < 5; ++mt) {
        const int bk = mh * 80 + mt * 16 + l15;
        rowbyte[mt] = (bk * 64 + lg * 16) ^ (((bk >> 1) & 3) << 4);
    }
    float4 wv[9];
#define WLOADM(pp) {                                                       \
        const float* wp = w + (size_t)((i * 32) + j0 + (pp)) * (COUT * FDIM); \
        _Pragma("unroll")                                                  \
        for (int q = 0; q < 9; ++q) {                                      \
            const int g  = tid + q * 512;                                  \
            const int o2 = g / 72;                                         \
            const int f4 = (g - o2 * 72) * 4;                              \
            wv[q] = *reinterpret_cast<const float4*>(wp + o2 * FDIM + f4); \
        } }
    WLOADM(0)
    {
#pragma unroll
        for (int r = 0; r < 15; ++r) {
            const int u   = tid + r * 512;
            const int s   = u / 1920;
            const int rem = u - s * 1920;
            const int pl  = rem / 640;
            const int cu  = rem - pl * 640;
            const short* src = xc + (size_t)((i + pl) * HP + (j0 + s)) * PLANE + cu * 8;
            gl_lds16(src, Sl + (size_t)u * 8);
        }
    }
    const f32x4 z4 = {0.f, 0.f, 0.f, 0.f};
#pragma unroll
    for (int p = 0; p < 4; ++p) {
#pragma unroll
        for (int q = 0; q < 9; ++q) {
            const int g  = tid + q * 512;
            const int o2 = g / 72;
            const int f4 = (g - o2 * 72) * 4;
            const float vv[4] = {wv[q].x, wv[q].y, wv[q].z, wv[q].w};
            short* wrow = WL + o2 * FPAD;
#pragma unroll
            for (int e = 0; e < 4; ++e) {
                const int f = f4 + e; const int c = f / 9;
                const int cell = f - c * 9;
                wrow[cell * 32 + c] = (short)f2bf(vv[e]);
            }
        }
        __syncthreads();
        if (p < 3) WLOADM(p + 1)
        if (p == 1 || p == 2) {
            const int s  = p - 1;
            const int jw = j0 + 4 + s;
#pragma unroll
            for (int r = 0; r < 4; ++r) {
                const int u = tid + r * 512;
                if (u < 1920) {
                    const int pl = u / 640;
                    const int cu = u - pl * 640;
                    const short* src = xc + (size_t)((i + pl) * HP + jw) * PLANE + cu * 8;
                    gl_lds16(src, Sl + (size_t)(s * SLOT_SH) + (size_t)u * 8);
                }
            }
        }
        f32x4 acc0 = z4, acc1 = z4, acc2 = z4, acc3 = z4, acc4 = z4;
        const short* bp = WL + (nt * 16 + l15) * FPAD + lg8;
#pragma unroll
        for (int kc = 0; kc < 9; ++kc) {
            const int kh   = kc / 3;
            const int kw   = kc - kh * 3;
            const int slot = (p + kw) & 3;
            const char* ab = (const char*)Sl + slot * (SLOT_SH * 2) + kh * (PLANE * 2);
            const bf16x8 b  = *reinterpret_cast<const bf16x8*>(bp + kc * 32);
            const bf16x8 a0 = *reinterpret_cast<const bf16x8*>(ab + rowbyte[0]);
            const bf16x8 a1 = *reinterpret_cast<const bf16x8*>(ab + rowbyte[1]);
            const bf16x8 a2 = *reinterpret_cast<const bf16x8*>(ab + rowbyte[2]);
            const bf16x8 a3 = *reinterpret_cast<const bf16x8*>(ab + rowbyte[3]);
            const bf16x8 a4 = *reinterpret_cast<const bf16x8*>(ab + rowbyte[4]);
            acc0 = __builtin_amdgcn_mfma_f32_16x16x32_bf16(a0, b, acc0, 0, 0, 0);
            acc1 = __builtin_amdgcn_mfma_f32_16x16x32_bf16(a1, b, acc1, 0, 0, 0);
            acc2 = __builtin_amdgcn_mfma_f32_16x16x32_bf16(a2, b, acc2, 0, 0, 0);
            acc3 = __builtin_amdgcn_mfma_f32_16x16x32_bf16(a3, b, acc3, 0, 0, 0);
            acc4 = __builtin_amdgcn_mfma_f32_16x16x32_bf16(a4, b, acc4, 0, 0, 0);
        }
        {
            const int pix = i * 32 + j0 + p;
            const int o3  = nt * 16 + l15;
            const size_t cb = ((size_t)pix * COUT + o3) * NBK + mh * 80 + lg * 4;
#define ST1(a, mt) { s16x4 s_;                                             \
            s_.x = (short)f2bf(a[0]); s_.y = (short)f2bf(a[1]);            \
            s_.z = (short)f2bf(a[2]); s_.w = (short)f2bf(a[3]);            \
            *reinterpret_cast<s16x4*>(co + cb + (mt) * 16) = s_; }
            ST1(acc0, 0) ST1(acc1, 1) ST1(acc2, 2) ST1(acc3, 3) ST1(acc4, 4)
#undef ST1
        }
        __syncthreads();
    }
#undef WLOADM
}

__global__ __launch_bounds__(256) void t2_kernel(
    const short* __restrict__ co,
    const float* __restrict__ bias,
    float* __restrict__ out)
{
    __shared__ short tl[32][36];
    const int b    = blockIdx.x;
    const int o    = b & 63;
    const int rest = b >> 6;
    const int bkT  = rest % 5;
    const int pixT = rest / 5;
    const int tid  = threadIdx.x;
    {
        const int p  = tid >> 3;
        const int bq = tid & 7;
        const int pix = pixT * 32 + p;
        const s16x4 v = *reinterpret_cast<const s16x4*>(
            co + ((size_t)pix * COUT + o) * NBK + bkT * 32 + bq * 4);
        *reinterpret_cast<s16x4*>(&tl[p][bq * 4]) = v;
    }
    __syncthreads();
    {
        const int bb = tid >> 3;
        const int pq = tid & 7;
        const int bk = bkT * 32 + bb;
        const int k  = bk % 10;
        const size_t pbase = (size_t)pixT * 32 + pq * 4;
        const float4 bv = *reinterpret_cast<const float4*>(
            bias + ((size_t)(k * COUT + o) << 10) + pbase);
        float4 r;
        r.x = bf2f(tl[pq * 4 + 0][bb]) + bv.x;
        r.y = bf2f(tl[pq * 4 + 1][bb]) + bv.y;
        r.z = bf2f(tl[pq * 4 + 2][bb]) + bv.z;
        r.w = bf2f(tl[pq * 4 + 3][bb]) + bv.w;
        *reinterpret_cast<float4*>(out + ((size_t)(bk * COUT + o) << 10) + pbase) = r;
    }
}

// ================= R3 fallback (proven; needs 10 MB) =================
__global__ __launch_bounds__(256) void xpose_kernel(
    const float* __restrict__ x, short* __restrict__ xc)
{
    __shared__ short tile[HW][36];
    const int bid = blockIdx.x;
    const int bk  = bid >> 5;
    const int h   = bid & 31;
    const int tid = threadIdx.x;
    {
        const int c  = tid >> 3;
        const int w4 = (tid & 7) * 4;
        const float4 v = *reinterpret_cast<const float4*>(
            x + (size_t)(bk * 32 + c) * 1024 + h * 32 + w4);
        tile[w4 + 0][c] = (short)f2bf(v.x);
        tile[w4 + 1][c] = (short)f2bf(v.y);
        tile[w4 + 2][c] = (short)f2bf(v.z);
        tile[w4 + 3][c] = (short)f2bf(v.w);
    }
    __syncthreads();
    {
        const int w  = tid >> 3;
        const int cq = tid & 7;
        const uint2 pk = *reinterpret_cast<const uint2*>(&tile[w][cq * 4]);
        *reinterpret_cast<uint2*>(
            xc + ((size_t)(bk * 1024 + h * 32 + w) * 32 + cq * 4)) = pk;
    }
}

__global__ __launch_bounds__(512, 4) void local2d_mfma2_kernel(
    const short* __restrict__ xc,
    const float* __restrict__ w,
    const float* __restrict__ bias,
    float* __restrict__ out)
{
    __shared__ short Wl[COUT * FPAD];
    const int hb  = blockIdx.x;
    const int lb  = (hb & 7) * 128 + (hb >> 3);
    const int i   = lb >> 5;
    const int j   = lb & 31;
    const int pix = i * HW + j;
    const int tid = threadIdx.x;
    {
        const float* wp = w + (size_t)pix * (COUT * FDIM);
#pragma unroll
        for (int p = 0; p < 9; ++p) {
            const int g  = tid + p * 512;
            const int o  = g / 72;
            const int f4 = (g - o * 72) * 4;
            const float4 v = *reinterpret_cast<const float4*>(wp + o * FDIM + f4);
            const float vv[4] = {v.x, v.y, v.z, v.w};
            short* wrow = &Wl[o * FPAD];
#pragma unroll
            for (int e = 0; e < 4; ++e) {
                const int f    = f4 + e;
                const int c    = f / 9;
                const int cell = f - c * 9;
                wrow[cell * 32 + c] = (short)f2bf(vv[e]);
            }
        }
    }
    __syncthreads();
    const int wave = tid >> 6;
    const int lane = tid & 63;
    const int nt   = wave & 3;
    const int mh   = wave >> 2;
    const int l15  = lane & 15;
    const int lg8  = (lane >> 4) * 8;
    f32x4 acc[5];
#pragma unroll
    for (int mt = 0; mt < 5; ++mt)
#pragma unroll
        for (int r = 0; r < 4; ++r) acc[mt][r] = 0.f;
    const short* xb[5];
#pragma unroll
    for (int mt = 0; mt < 5; ++mt) {
        const int bk = mh * 80 + mt * 16 + l15;
        xb[mt] = xc + (size_t)bk * (HW * HW * CIN) + lg8;
    }
    const short* bp = &Wl[(nt * 16 + l15) * FPAD + lg8];
#pragma unroll
    for (int kc = 0; kc < 9; ++kc) {
        const int kh = kc / 3;
        const int kw = kc - kh * 3;
        const int ih = i - 1 + kh;
        const int jw = j - 1 + kw;
        if ((unsigned)ih >= (unsigned)HW || (unsigned)jw >= (unsigned)HW)
            continue;
        const bf16x8 b = *reinterpret_cast<const bf16x8*>(bp + kc * 32);
        const int xoff = (ih * HW + jw) * CIN;
#pragma unroll
        for (int mt = 0; mt < 5; ++mt) {
            const bf16x8 a = *reinterpret_cast<const bf16x8*>(xb[mt] + xoff);
            acc[mt] = __builtin_amdgcn_mfma_f32_16x16x32_bf16(a, b, acc[mt], 0, 0, 0);
        }
    }
    const int o  = nt * 16 + l15;
    const int r0 = (lane >> 4) * 4;
#pragma unroll
    for (int mt = 0; mt < 5; ++mt) {
        const int bk0 = mh * 80 + mt * 16 + r0;
#pragma unroll
        for (int r = 0; r < 4; ++r) {
            const int bk = bk0 + r;
            const int k  = bk % 10;
            out[((size_t)(bk * COUT + o) << 10) + pix] =
                acc[mt][r] + bias[((size_t)(k * COUT + o) << 10) + pix];
        }
    }
}

extern "C" void kernel_launch(void* const* d_in, const int* in_sizes, int n_in,
                              void* d_out, int out_size, void* d_ws, size_t ws_size,
                              hipStream_t stream) {
    const float* x    = (const float*)d_in[0];
    const float* w    = (const float*)d_in[1];
    const float* bias = (const float*)d_in[2];
    float* out        = (float*)d_out;

    if (ws_size >= XC_BYTES + WP_BYTES) {
        short* xc    = (short*)d_ws;
        short* wpack = (short*)((char*)d_ws + XC_BYTES);
        hipLaunchKernelGGL(hz_kernel, dim3(132), dim3(256), 0, stream, xc);
        hipLaunchKernelGGL(t1l_kernel, dim3(5120), dim3(256), 0, stream, x, xc);
        hipLaunchKernelGGL(t3_kernel, dim3(1024), dim3(256), 0, stream, w, wpack);
        hipLaunchKernelGGL(local2d_f_kernel, dim3(256), dim3(512), 0, stream,
                           xc, wpack, bias, out);
    } else if (ws_size >= XC_BYTES + CO_BYTES) {
        short* xc = (short*)d_ws;
        short* co = (short*)((char*)d_ws + XC_BYTES);
        hipLaunchKernelGGL(hz_kernel, dim3(132), dim3(256), 0, stream, xc);
        hipLaunchKernelGGL(t1s_kernel, dim3(5120), dim3(256), 0, stream, x, xc);
        hipLaunchKernelGGL(local2d_m_kernel, dim3(256), dim3(512), 0, stream,
                           xc, w, co);
        hipLaunchKernelGGL(t2_kernel, dim3(10240), dim3(256), 0, stream,
                           co, bias, out);
    } else {
        short* xc = (short*)d_ws;
        hipLaunchKernelGGL(xpose_kernel, dim3(5120), dim3(256), 0, stream, x, xc);
        hipLaunchKernelGGL(local2d_mfma2_kernel, dim3(1024), dim3(512), 0, stream,
                           xc, w, bias, out);
    }
}

// Round 14
// 57.694 us; speedup vs baseline: 1.1771x; 1.1771x over previous
//
#include <hip/hip_runtime.h>

// VecLocal2d R14 = R9 (best, 51.1us) with t2+co DELETED: accumulators for
// all 4 pixels retained in VGPRs, one fused epilogue (LDS col transpose
// overlaid on the dead A-slot region -> bias-fused float4-over-pix out
// stores). Saves 63 MB of traffic + one dispatch. Phases have no global
// stores -> re-audited vmcnt ledger below.
//
// Ledger (per wave):
//  pro:  W0[9] S[15]          -> VM(15)=W0; scat0; W1[9] -> VM(9)=S; BAR
//  ph0:  C0                   -> BAR; VM(0)=W1; scat1; W2[9]; BAR
//  ph1:  R0[4]; C1            -> BAR; VM(4)=W2; scat2; W3[9]; VM(9)=R0; BAR
//  ph2:  R1[4]; C2            -> BAR; VM(4)=W3; scat3; VM(0)=R1; BAR
//  ph3:  C3                   -> BAR (slots dead)
//  epi:  col writes; lgkm0+BAR; 20x {4 col reads + bias float4 + out float4}
// hz/t1(pre-swizzled)/R3-fallback verbatim from R9 (passed, absmax 0.03125).

#define HW    32
#define CIN   32
#define COUT  64
#define FDIM  288
#define FPAD  296
#define NBK   160
#define HP    34
#define PLANE (NBK * CIN)      // 5120 shorts per (ih,jw) plane
#define SLOT_SH (3 * PLANE)    // 15360 shorts per jw-slot
#define WOFF  (4 * SLOT_SH)    // 61440 shorts: W region start
#define BKP   164              // col pad: 328B row -> 8B-aligned, spread banks

using f32x4  = __attribute__((ext_vector_type(4))) float;
using bf16x8 = __attribute__((ext_vector_type(8))) short;
using s16x4  = __attribute__((ext_vector_type(4))) short;

static __device__ inline unsigned short f2bf(float f) {
    unsigned u = __float_as_uint(f);
    u += 0x7FFFu + ((u >> 16) & 1u);   // round-to-nearest-even
    return (unsigned short)(u >> 16);
}
static __device__ inline float bf2f(short h) {
    return __uint_as_float(((unsigned)(unsigned short)h) << 16);
}
static __device__ inline void gl_lds16(const short* src, short* dst) {
    __builtin_amdgcn_global_load_lds(
        (const __attribute__((address_space(1))) unsigned int*)src,
        (__attribute__((address_space(3))) unsigned int*)dst, 16, 0, 0);
}
static constexpr size_t XC_BYTES = (size_t)HP * HP * PLANE * 2;   // 11,837,440

// ---- hz ----
__global__ __launch_bounds__(256) void hz_kernel(short* __restrict__ xc)
{
    const int id = blockIdx.x;
    int h, w;
    if (id < 34)      { h = 0;  w = id; }
    else if (id < 68) { h = 33; w = id - 34; }
    else { const int e = id - 68; h = 1 + (e >> 1); w = (e & 1) * 33; }
    uint2* p = reinterpret_cast<uint2*>(xc + (size_t)(h * HP + w) * PLANE);
    const uint2 z = {0u, 0u};
#pragma unroll
    for (int r = 0; r < 5; ++r)
        p[threadIdx.x + r * 256] = z;
}

// ---- t1 (pre-swizzled planes) ----
__global__ __launch_bounds__(256) void t1_kernel(
    const float* __restrict__ x, short* __restrict__ xc)
{
    __shared__ short tile[HW][36];
    const int bid = blockIdx.x;
    const int bk  = bid >> 5;
    const int h   = bid & 31;
    const int tid = threadIdx.x;
    {
        const int c  = tid >> 3;
        const int w4 = (tid & 7) * 4;
        const float4 v = *reinterpret_cast<const float4*>(
            x + (size_t)(bk * 32 + c) * 1024 + h * 32 + w4);
        tile[w4 + 0][c] = (short)f2bf(v.x);
        tile[w4 + 1][c] = (short)f2bf(v.y);
        tile[w4 + 2][c] = (short)f2bf(v.z);
        tile[w4 + 3][c] = (short)f2bf(v.w);
    }
    __syncthreads();
    {
        const int w  = tid >> 3;
        const int cq = tid & 7;
        const uint2 pk = *reinterpret_cast<const uint2*>(&tile[w][cq * 4]);
        const int sidx = bk * 32 + ((cq * 4) ^ (((bk >> 1) & 3) << 3));
        *reinterpret_cast<uint2*>(
            xc + (size_t)((h + 1) * HP + (w + 1)) * PLANE + sidx) = pk;
    }
}

// ---- main ----
#define SB()  __builtin_amdgcn_sched_barrier(0)
#define VM(n) { asm volatile("s_waitcnt vmcnt(" #n ")" ::: "memory"); SB(); }
#define LG0BAR() { asm volatile("s_waitcnt lgkmcnt(0)" ::: "memory"); SB(); \
                   __builtin_amdgcn_s_barrier(); SB(); }
#define BARA() { asm volatile("s_waitcnt lgkmcnt(0)" ::: "memory"); SB(); \
                 __builtin_amdgcn_s_barrier(); SB(); }

__global__ __launch_bounds__(512) void local2d_e_kernel(
    const short* __restrict__ xc,
    const float* __restrict__ w,
    const float* __restrict__ bias,
    float* __restrict__ out)
{
    __shared__ __align__(1024) short Sl[WOFF + COUT * FPAD];  // 160,768 B

    const int hb = blockIdx.x;                  // 256 = i(32) * jt(8)
    const int lb = (hb & 7) * 32 + (hb >> 3);   // same-i blocks share an XCD
    const int i  = lb >> 3;
    const int jt = lb & 7;
    const int j0 = jt * 4;
    const int tid = threadIdx.x;

    const int wave = tid >> 6;
    const int lane = tid & 63;
    const int nt   = wave & 3;
    const int mh   = wave >> 2;
    const int l15  = lane & 15;
    const int lg   = lane >> 4;
    const int lg8  = lg * 8;

    short* WL = Sl + WOFF;

    int rowbyte[5];
#pragma unroll
    for (int mt = 0; mt < 5; ++mt) {
        const int bk = mh * 80 + mt * 16 + l15;
        rowbyte[mt] = (bk * 64 + lg * 16) ^ (((bk >> 1) & 3) << 4);
    }

    float4 wv0[9], wv1[9];
    const f32x4 z4 = {0.f, 0.f, 0.f, 0.f};
    f32x4 acc[4][5];                  // [pixel][mt], ALL literal-indexed
#pragma unroll
    for (int p = 0; p < 4; ++p)
#pragma unroll
        for (int mt = 0; mt < 5; ++mt) acc[p][mt] = z4;

#define WISSUE(dst, pp) {                                                  \
        const float* wp = w + (size_t)((i * 32) + j0 + (pp)) * (COUT * FDIM); \
        _Pragma("unroll")                                                  \
        for (int q = 0; q < 9; ++q) {                                      \
            const int g  = tid + q * 512;                                  \
            const int o2 = g / 72;                                         \
            const int f4 = (g - o2 * 72) * 4;                              \
            dst[q] = *reinterpret_cast<const float4*>(wp + o2 * FDIM + f4);\
        } SB(); }

#define SCATTER(src) {                                                     \
        _Pragma("unroll")                                                  \
        for (int q = 0; q < 9; ++q) {                                      \
            const int g  = tid + q * 512;                                  \
            const int o2 = g / 72;                                         \
            const int f4 = (g - o2 * 72) * 4;                              \
            const float vv[4] = {src[q].x, src[q].y, src[q].z, src[q].w};  \
            short* wrow = WL + o2 * FPAD;                                  \
            _Pragma("unroll")                                              \
            for (int e = 0; e < 4; ++e) {                                  \
                const int f = f4 + e; const int c = f / 9;                 \
                const int cell = f - c * 9;                                \
                wrow[cell * 32 + c] = (short)f2bf(vv[e]); } } SB(); }

#define RISSUE(s) {                                                        \
        if (tid < 480) {                                                   \
            _Pragma("unroll")                                              \
            for (int r = 0; r < 4; ++r) {                                  \
                const int u  = tid + r * 480;                              \
                const int pl = u / 640;                                    \
                const int cu = u - pl * 640;                               \
                const short* src = xc + (size_t)((i + pl) * HP + (j0 + 4 + (s))) * PLANE + cu * 8; \
                gl_lds16(src, Sl + (size_t)((s) * SLOT_SH) + (size_t)u * 8); \
            } } SB(); }

#define COMPUTE(p) {                                                       \
        const short* bp = WL + (nt * 16 + l15) * FPAD + lg8;               \
        __builtin_amdgcn_s_setprio(1);                                     \
        _Pragma("unroll")                                                  \
        for (int kc = 0; kc < 9; ++kc) {                                   \
            const int kh   = kc / 3;                                       \
            const int kw   = kc - kh * 3;                                  \
            const int slot = ((p) + kw) & 3;                               \
            const char* ab = (const char*)Sl + slot * (SLOT_SH * 2) + kh * (PLANE * 2); \
            const bf16x8 b  = *reinterpret_cast<const bf16x8*>(bp + kc * 32); \
            const bf16x8 a0 = *reinterpret_cast<const bf16x8*>(ab + rowbyte[0]); \
            const bf16x8 a1 = *reinterpret_cast<const bf16x8*>(ab + rowbyte[1]); \
            const bf16x8 a2 = *reinterpret_cast<const bf16x8*>(ab + rowbyte[2]); \
            const bf16x8 a3 = *reinterpret_cast<const bf16x8*>(ab + rowbyte[3]); \
            const bf16x8 a4 = *reinterpret_cast<const bf16x8*>(ab + rowbyte[4]); \
            acc[p][0] = __builtin_amdgcn_mfma_f32_16x16x32_bf16(a0, b, acc[p][0], 0, 0, 0); \
            acc[p][1] = __builtin_amdgcn_mfma_f32_16x16x32_bf16(a1, b, acc[p][1], 0, 0, 0); \
            acc[p][2] = __builtin_amdgcn_mfma_f32_16x16x32_bf16(a2, b, acc[p][2], 0, 0, 0); \
            acc[p][3] = __builtin_amdgcn_mfma_f32_16x16x32_bf16(a3, b, acc[p][3], 0, 0, 0); \
            acc[p][4] = __builtin_amdgcn_mfma_f32_16x16x32_bf16(a4, b, acc[p][4], 0, 0, 0); \
        }                                                                  \
        __builtin_amdgcn_s_setprio(0); }

    // ================= prologue =================
    WISSUE(wv0, 0)                           // [W0:9]
    {
#pragma unroll
        for (int r = 0; r < 15; ++r) {       // SLOTS
            const int u   = tid + r * 512;
            const int s   = u / 1920;
            const int rem = u - s * 1920;
            const int pl  = rem / 640;
            const int cu  = rem - pl * 640;
            const short* src = xc + (size_t)((i + pl) * HP + (j0 + s)) * PLANE + cu * 8;
            gl_lds16(src, Sl + (size_t)u * 8);
        }
        SB();
    }                                        // [W0:9 S:15] = 24
    VM(15)                                   // W0 done
    SCATTER(wv0)
    WISSUE(wv1, 1)                           // [S:15 W1:9]
    VM(9)                                    // S done (W1 in flight)
    LG0BAR()                                 // WL=w(0), slots ready

    // ================= phase 0 =================
    COMPUTE(0)
    BARA()
    VM(0)                                    // W1 done
    SCATTER(wv1)
    WISSUE(wv0, 2)                           // [W2:9]
    LG0BAR()                                 // WL=w(1)

    // ================= phase 1 =================
    RISSUE(0)                                // [W2:9 R0:4]
    COMPUTE(1)
    BARA()
    VM(4)                                    // W2 done
    SCATTER(wv0)
    WISSUE(wv1, 3)                           // [R0:4 W3:9]
    VM(9)                                    // R0 done
    LG0BAR()                                 // WL=w(2), slot0 ready

    // ================= phase 2 =================
    RISSUE(1)                                // [W3:9 R1:4]
    COMPUTE(2)
    BARA()
    VM(4)                                    // W3 done
    SCATTER(wv1)
    VM(0)                                    // R1 done
    LG0BAR()                                 // WL=w(3), slot1 ready

    // ================= phase 3 =================
    COMPUTE(3)
    BARA()                                   // all slot reads complete

    // ================= fused epilogue =================
    {
        short* col = Sl;                     // overlay dead slot region
        const int o3 = nt * 16 + l15;
#pragma unroll
        for (int p = 0; p < 4; ++p) {
#pragma unroll
            for (int mt = 0; mt < 5; ++mt) {
                s16x4 s_;
                s_.x = (short)f2bf(acc[p][mt][0]);
                s_.y = (short)f2bf(acc[p][mt][1]);
                s_.z = (short)f2bf(acc[p][mt][2]);
                s_.w = (short)f2bf(acc[p][mt][3]);
                *reinterpret_cast<s16x4*>(
                    &col[(p * COUT + o3) * BKP + mh * 80 + mt * 16 + lg * 4]) = s_;
            }
        }
        LG0BAR()

        const int pix0 = i * 32 + j0;
#pragma unroll
        for (int s = 0; s < 20; ++s) {
            const int id = tid + s * 512;    // 10240 (bk,o) pairs
            const int o  = id & 63;
            const int bk = id >> 6;
            const int k  = bk % 10;
            const float4 bv = *reinterpret_cast<const float4*>(
                bias + (((size_t)(k * COUT + o)) << 10) + pix0);
            float4 r;
            r.x = bf2f(col[(0 * COUT + o) * BKP + bk]) + bv.x;
            r.y = bf2f(col[(1 * COUT + o) * BKP + bk]) + bv.y;
            r.z = bf2f(col[(2 * COUT + o) * BKP + bk]) + bv.z;
            r.w = bf2f(col[(3 * COUT + o) * BKP + bk]) + bv.w;
            *reinterpret_cast<float4*>(
                out + (((size_t)(bk * COUT + o)) << 10) + pix0) = r;
        }
    }

#undef WISSUE
#undef SCATTER
#undef RISSUE
#undef COMPUTE
}

// ================= R3 fallback (proven; needs 10 MB ws) =================
__global__ __launch_bounds__(256) void xpose_kernel(
    const float* __restrict__ x, short* __restrict__ xc)
{
    __shared__ short tile[HW][36];
    const int bid = blockIdx.x;
    const int bk  = bid >> 5;
    const int h   = bid & 31;
    const int tid = threadIdx.x;
    {
        const int c  = tid >> 3;
        const int w4 = (tid & 7) * 4;
        const float4 v = *reinterpret_cast<const float4*>(
            x + (size_t)(bk * 32 + c) * 1024 + h * 32 + w4);
        tile[w4 + 0][c] = (short)f2bf(v.x);
        tile[w4 + 1][c] = (short)f2bf(v.y);
        tile[w4 + 2][c] = (short)f2bf(v.z);
        tile[w4 + 3][c] = (short)f2bf(v.w);
    }
    __syncthreads();
    {
        const int w  = tid >> 3;
        const int cq = tid & 7;
        const uint2 pk = *reinterpret_cast<const uint2*>(&tile[w][cq * 4]);
        *reinterpret_cast<uint2*>(
            xc + ((size_t)(bk * 1024 + h * 32 + w) * 32 + cq * 4)) = pk;
    }
}

__global__ __launch_bounds__(512, 4) void local2d_mfma2_kernel(
    const short* __restrict__ xc,
    const float* __restrict__ w,
    const float* __restrict__ bias,
    float* __restrict__ out)
{
    __shared__ short Wl[COUT * FPAD];
    const int hb  = blockIdx.x;
    const int lb  = (hb & 7) * 128 + (hb >> 3);
    const int i   = lb >> 5;
    const int j   = lb & 31;
    const int pix = i * HW + j;
    const int tid = threadIdx.x;
    {
        const float* wp = w + (size_t)pix * (COUT * FDIM);
#pragma unroll
        for (int p = 0; p < 9; ++p) {
            const int g  = tid + p * 512;
            const int o  = g / 72;
            const int f4 = (g - o * 72) * 4;
            const float4 v = *reinterpret_cast<const float4*>(wp + o * FDIM + f4);
            const float vv[4] = {v.x, v.y, v.z, v.w};
            short* wrow = &Wl[o * FPAD];
#pragma unroll
            for (int e = 0; e < 4; ++e) {
                const int f    = f4 + e;
                const int c    = f / 9;
                const int cell = f - c * 9;
                wrow[cell * 32 + c] = (short)f2bf(vv[e]);
            }
        }
    }
    __syncthreads();
    const int wave = tid >> 6;
    const int lane = tid & 63;
    const int nt   = wave & 3;
    const int mh   = wave >> 2;
    const int l15  = lane & 15;
    const int lg8  = (lane >> 4) * 8;
    f32x4 acc[5];
#pragma unroll
    for (int mt = 0; mt < 5; ++mt)
#pragma unroll
        for (int r = 0; r < 4; ++r) acc[mt][r] = 0.f;
    const short* xb[5];
#pragma unroll
    for (int mt = 0; mt < 5; ++mt) {
        const int bk = mh * 80 + mt * 16 + l15;
        xb[mt] = xc + (size_t)bk * (HW * HW * CIN) + lg8;
    }
    const short* bp = &Wl[(nt * 16 + l15) * FPAD + lg8];
#pragma unroll
    for (int kc = 0; kc < 9; ++kc) {
        const int kh = kc / 3;
        const int kw = kc - kh * 3;
        const int ih = i - 1 + kh;
        const int jw = j - 1 + kw;
        if ((unsigned)ih >= (unsigned)HW || (unsigned)jw >= (unsigned)HW)
            continue;
        const bf16x8 b = *reinterpret_cast<const bf16x8*>(bp + kc * 32);
        const int xoff = (ih * HW + jw) * CIN;
#pragma unroll
        for (int mt = 0; mt < 5; ++mt) {
            const bf16x8 a = *reinterpret_cast<const bf16x8*>(xb[mt] + xoff);
            acc[mt] = __builtin_amdgcn_mfma_f32_16x16x32_bf16(a, b, acc[mt], 0, 0, 0);
        }
    }
    const int o  = nt * 16 + l15;
    const int r0 = (lane >> 4) * 4;
#pragma unroll
    for (int mt = 0; mt < 5; ++mt) {
        const int bk0 = mh * 80 + mt * 16 + r0;
#pragma unroll
        for (int r = 0; r < 4; ++r) {
            const int bk = bk0 + r;
            const int k  = bk % 10;
            out[((size_t)(bk * COUT + o) << 10) + pix] =
                acc[mt][r] + bias[((size_t)(k * COUT + o) << 10) + pix];
        }
    }
}

extern "C" void kernel_launch(void* const* d_in, const int* in_sizes, int n_in,
                              void* d_out, int out_size, void* d_ws, size_t ws_size,
                              hipStream_t stream) {
    const float* x    = (const float*)d_in[0];
    const float* w    = (const float*)d_in[1];
    const float* bias = (const float*)d_in[2];
    float* out        = (float*)d_out;

    if (ws_size >= XC_BYTES) {
        short* xc = (short*)d_ws;
        hipLaunchKernelGGL(hz_kernel, dim3(132), dim3(256), 0, stream, xc);
        hipLaunchKernelGGL(t1_kernel, dim3(5120), dim3(256), 0, stream, x, xc);
        hipLaunchKernelGGL(local2d_e_kernel, dim3(256), dim3(512), 0, stream,
                           xc, w, bias, out);
    } else {
        short* xc = (short*)d_ws;
        hipLaunchKernelGGL(xpose_kernel, dim3(5120), dim3(256), 0, stream, x, xc);
        hipLaunchKernelGGL(local2d_mfma2_kernel, dim3(1024), dim3(512), 0, stream,
                           xc, w, bias, out);
    }
}